// Round 3
// baseline (186.498 us; speedup 1.0000x reference)
//
#include <hip/hip_runtime.h>
#include <stdint.h>

typedef short bf16x8 __attribute__((ext_vector_type(8)));
typedef float f32x4 __attribute__((ext_vector_type(4)));

#define NROWS 16384
#define K1DIM 256
#define N1DIM 2048
#define N2DIM 96
#define MARGIN 0.03f

#define GLD16(g, l) __builtin_amdgcn_global_load_lds( \
    (const __attribute__((address_space(1))) uint32_t*)(g), \
    (__attribute__((address_space(3))) uint32_t*)(l), 16, 0, 0)

__device__ __forceinline__ ushort f2bf(float x) {
  union { float f; uint32_t u; } c; c.f = x;
  uint32_t u = c.u;
  return (ushort)((u + 0x7FFFu + ((u >> 16) & 1u)) >> 16);
}

// ---------------- K0: convert inputs to bf16 (x2, Wl1^T, W2sel^T, Wb1^T) ---
__global__ __launch_bounds__(256) void k0_convert(
    const float* __restrict__ bd, const float* __restrict__ Wl1,
    const float* __restrict__ Wl2, const float* __restrict__ Wb1,
    ushort* __restrict__ x2bf, ushort* __restrict__ wl1t,
    ushort* __restrict__ w2t, ushort* __restrict__ wb1t) {
  int i = blockIdx.x * 256 + threadIdx.x;
  if (i < NROWS * 256) x2bf[i] = f2bf(bd[i]);
  if (i < 2048 * 256) {  // wl1t[n][k] = Wl1[k][n]
    int n = i >> 8, k = i & 255;
    wl1t[i] = f2bf(Wl1[k * 2048 + n]);
  }
  if (i < 96 * 2048) {   // w2t[j][k] = Wl2[k][colmap(j)]; j<48 -> leaf0, else leaf31
    int j = i >> 11, k = i & 2047;
    int col = (j < 48) ? j : (1440 + j);  // 1488 + (j-48)
    w2t[i] = f2bf(Wl2[k * 1536 + col]);
  }
  if (i < 512 * 128) {   // wb1t[j][m] = Wb1[m][j]
    int j = i >> 7, m = i & 127;
    wb1t[i] = f2bf(Wb1[m * 512 + j]);
  }
}

// ---------------- K1a: branch scores via bf16 MFMA -------------------------
__global__ __launch_bounds__(256) void k1a_score(
    const ushort* __restrict__ x2bf, const ushort* __restrict__ wb1t,
    const float* __restrict__ bb1, const float* __restrict__ Wb2,
    float* __restrict__ part) {
  __shared__ __align__(1024) ushort As[128 * 64];
  __shared__ __align__(1024) ushort Bs[128 * 64];
  const int t = threadIdx.x, ln = t & 63, wv = t >> 6;
  const int m0 = blockIdx.y << 7;
  const int n0 = blockIdx.x << 7;
  const int wm = (wv >> 1) << 6, wn = (wv & 1) << 6;
  const int rsub = ln >> 3, kc8 = ln & 7;
  const int q = ln >> 4, rr = ln & 15;

  f32x4 acc[4][4] = {};

  for (int k0 = 0; k0 < 128; k0 += 64) {
#pragma unroll
    for (int i = 0; i < 4; i++) {
      int inst = (wv << 2) + i;
      int row = (inst << 3) + rsub;
      GLD16(x2bf + (size_t)(m0 + row) * 256 + k0 + (kc8 << 3), As + (inst << 9));
      GLD16(wb1t + (size_t)(n0 + row) * 128 + k0 + (kc8 << 3), Bs + (inst << 9));
    }
    __syncthreads();
#pragma unroll
    for (int kk = 0; kk < 2; kk++) {
      int kb = ((kk << 2) + q) << 3;
      bf16x8 af[4], bfr[4];
#pragma unroll
      for (int mi = 0; mi < 4; mi++)
        af[mi] = *(const bf16x8*)(As + (((wm + (mi << 4) + rr)) << 6) + kb);
#pragma unroll
      for (int ni = 0; ni < 4; ni++)
        bfr[ni] = *(const bf16x8*)(Bs + (((wn + (ni << 4) + rr)) << 6) + kb);
#pragma unroll
      for (int mi = 0; mi < 4; mi++)
#pragma unroll
        for (int ni = 0; ni < 4; ni++)
          acc[mi][ni] = __builtin_amdgcn_mfma_f32_16x16x32_bf16(
              af[mi], bfr[ni], acc[mi][ni], 0, 0, 0);
    }
    __syncthreads();
  }

  float s4[4][4] = {};
#pragma unroll
  for (int ni = 0; ni < 4; ni++) {
    int col = n0 + wn + (ni << 4) + rr;
    float bias = bb1[col];
    float wdv = Wb2[col * 2 + 1] - Wb2[col * 2];
#pragma unroll
    for (int mi = 0; mi < 4; mi++) {
      f32x4 a = acc[mi][ni];
#pragma unroll
      for (int v = 0; v < 4; v++)
        s4[mi][v] += fmaxf(a[v] + bias, 0.f) * wdv;
    }
  }
#pragma unroll
  for (int off = 1; off <= 8; off <<= 1)
#pragma unroll
    for (int mi = 0; mi < 4; mi++)
#pragma unroll
      for (int v = 0; v < 4; v++)
        s4[mi][v] += __shfl_xor(s4[mi][v], off);

  if (rr == 0) {
    float* dst = part + (size_t)(blockIdx.x * 2 + (wv & 1)) * NROWS +
                 m0 + wm + (q << 2);
#pragma unroll
    for (int mi = 0; mi < 4; mi++) {
      float4 v4 = make_float4(s4[mi][0], s4[mi][1], s4[mi][2], s4[mi][3]);
      *(float4*)(dst + (mi << 4)) = v4;
    }
  }
}

// ---------------- K1b: sum partials, classify, compact marginal rows -------
__global__ __launch_bounds__(256) void k1b_classify(
    const float* __restrict__ part, const float* __restrict__ bb2,
    int* __restrict__ router, int* __restrict__ list, int* __restrict__ counter) {
  int t = blockIdx.x * 256 + threadIdx.x;
  float s = bb2[1] - bb2[0];
#pragma unroll
  for (int i = 0; i < 8; i++) s += part[i * NROWS + t];
  router[t] = (s >= 0.f) ? 1 : 0;
  if (fabsf(s) < MARGIN) {
    int idx = atomicAdd(counter, 1);
    list[idx] = t;
  }
}

// ---------------- K1c: exact fp32 recheck of marginal rows -----------------
__global__ __launch_bounds__(256) void k1c_recheck(
    const float* __restrict__ bd, const float* __restrict__ Wb1,
    const float* __restrict__ Wb2, const float* __restrict__ bb1,
    const float* __restrict__ bb2, const int* __restrict__ list,
    const int* __restrict__ counter, int* __restrict__ router) {
  const int ln = threadIdx.x & 63;
  const int wid = (blockIdx.x * 256 + threadIdx.x) >> 6;
  const int count = *counter;
  const float c = bb2[1] - bb2[0];

  for (int base = wid * 4; base < count; base += 512 * 4) {
    int rows[4];
#pragma unroll
    for (int r = 0; r < 4; r++) {
      int idx = base + r;
      rows[r] = list[(idx < count) ? idx : base];
    }
    float acc[4][8];
#pragma unroll
    for (int r = 0; r < 4; r++)
#pragma unroll
      for (int u = 0; u < 8; u++) acc[r][u] = 0.f;

    for (int m = 0; m < 128; m++) {
      float w[8];
#pragma unroll
      for (int u = 0; u < 8; u++) w[u] = Wb1[m * 512 + (u << 6) + ln];
#pragma unroll
      for (int r = 0; r < 4; r++) {
        float x = bd[(size_t)rows[r] * 256 + m];
#pragma unroll
        for (int u = 0; u < 8; u++) acc[r][u] = fmaf(x, w[u], acc[r][u]);
      }
    }
    float sc[4];
#pragma unroll
    for (int r = 0; r < 4; r++) {
      float s = 0.f;
#pragma unroll
      for (int u = 0; u < 8; u++) {
        int j = (u << 6) + ln;
        float wd = Wb2[j * 2 + 1] - Wb2[j * 2];
        s += fmaxf(acc[r][u] + bb1[j], 0.f) * wd;
      }
#pragma unroll
      for (int off = 1; off <= 32; off <<= 1) s += __shfl_xor(s, off);
      sc[r] = s + c;
    }
    if (ln == 0) {
#pragma unroll
      for (int r = 0; r < 4; r++)
        if (base + r < count) router[rows[r]] = (sc[r] >= 0.f) ? 1 : 0;
    }
  }
}

// ---------------- K2: FUSED GEMM1+GEMM2, hl never hits HBM -----------------
// block: 64 rows x one 1024-col n-half. Per 128-col chunk:
//   G1: Ht[64x128] = relu(x2[64x256] @ Wl1[:,chunk] + b)   (MFMA, LDS-staged)
//   Ht -> bf16 -> padded LDS tile Hs[64][136]
//   G2: accP[64x96] += Ht @ w2sel[chunk,:]                  (MFMA, AGPR-resident)
__global__ __launch_bounds__(256) void k2_fused(
    const ushort* __restrict__ x2bf, const ushort* __restrict__ wl1t,
    const ushort* __restrict__ w2t, const float* __restrict__ bl1,
    float* __restrict__ P) {
  __shared__ __align__(1024) ushort As[64 * 64];        // x2 tile [r][k]
  __shared__ __align__(1024) ushort Bs[128 * 64];       // Wl1^T tile [n][k]
  __shared__ __align__(1024) ushort Ws[2 * 96 * 64];    // w2 tile [half][n][k]
  __shared__ __align__(1024) ushort Hs[64 * 136];       // hl tile [r][k], padded
  const int t = threadIdx.x, ln = t & 63, wv = t >> 6;
  const int ks2 = blockIdx.x;       // n-half: 0,1
  const int m0 = blockIdx.y << 6;   // 64-row block
  const int q = ln >> 4, rr = ln & 15;
  const int rsub = ln >> 3, kc8 = ln & 7;

  f32x4 accP[6] = {};

  for (int nc = 0; nc < 8; nc++) {
    const int n0 = (ks2 << 10) + (nc << 7);  // global col base of this chunk

    // stage Ws for this chunk: w2t[0..96][n0..n0+128] as two [96][64] halves
#pragma unroll
    for (int j = 0; j < 6; j++) {
      int inst = wv * 6 + j;              // 0..23
      int h = inst / 12;
      int r0 = (inst - h * 12) << 3;
      GLD16(w2t + (size_t)(r0 + rsub) * 2048 + n0 + (h << 6) + (kc8 << 3),
            Ws + h * 6144 + ((inst - h * 12) << 9));
    }

    f32x4 acc1[4][2] = {};
    for (int k0 = 0; k0 < K1DIM; k0 += 64) {
#pragma unroll
      for (int i = 0; i < 2; i++) {
        int inst = (wv << 1) + i;
        int row = (inst << 3) + rsub;
        GLD16(x2bf + (size_t)(m0 + row) * K1DIM + k0 + (kc8 << 3),
              As + (inst << 9));
      }
#pragma unroll
      for (int i = 0; i < 4; i++) {
        int inst = (wv << 2) + i;
        int row = (inst << 3) + rsub;
        GLD16(wl1t + (size_t)(n0 + row) * K1DIM + k0 + (kc8 << 3),
              Bs + (inst << 9));
      }
      __syncthreads();
#pragma unroll
      for (int kk = 0; kk < 2; kk++) {
        int kb = (kk << 5) + (q << 3);
        bf16x8 af[4], bfr[2];
#pragma unroll
        for (int mi = 0; mi < 4; mi++)
          af[mi] = *(const bf16x8*)(As + (((mi << 4) + rr) << 6) + kb);
#pragma unroll
        for (int ni = 0; ni < 2; ni++)
          bfr[ni] = *(const bf16x8*)(Bs + (((wv << 5) + (ni << 4) + rr) << 6) + kb);
#pragma unroll
        for (int mi = 0; mi < 4; mi++)
#pragma unroll
          for (int ni = 0; ni < 2; ni++)
            acc1[mi][ni] = __builtin_amdgcn_mfma_f32_16x16x32_bf16(
                af[mi], bfr[ni], acc1[mi][ni], 0, 0, 0);
      }
      __syncthreads();
    }

    // epilogue 1: bias + relu -> bf16 -> Hs (wave owns cols wv*32..wv*32+32)
#pragma unroll
    for (int ni = 0; ni < 2; ni++) {
      int lcol = (wv << 5) + (ni << 4) + rr;
      float bias = bl1[n0 + lcol];
#pragma unroll
      for (int mi = 0; mi < 4; mi++) {
        f32x4 a = acc1[mi][ni];
#pragma unroll
        for (int v = 0; v < 4; v++) {
          int lrow = (mi << 4) + (q << 2) + v;
          Hs[lrow * 136 + lcol] = f2bf(fmaxf(a[v] + bias, 0.f));
        }
      }
    }
    __syncthreads();

    // G2: accP[wave's 16 rows][96] += Hs @ Ws   (K=128 chunk)
#pragma unroll
    for (int kk = 0; kk < 4; kk++) {
      int half = kk >> 1;
      int k64 = (kk & 1) << 5;
      bf16x8 ha = *(const bf16x8*)(Hs + ((wv << 4) + rr) * 136 + (kk << 5) + (q << 3));
#pragma unroll
      for (int ni = 0; ni < 6; ni++) {
        bf16x8 wb = *(const bf16x8*)(Ws + half * 6144 +
                                     (((ni << 4) + rr) << 6) + k64 + (q << 3));
        accP[ni] = __builtin_amdgcn_mfma_f32_16x16x32_bf16(ha, wb, accP[ni], 0, 0, 0);
      }
    }
    __syncthreads();
  }

  // store P partial for this n-half
#pragma unroll
  for (int ni = 0; ni < 6; ni++) {
#pragma unroll
    for (int v = 0; v < 4; v++) {
      int row = m0 + (wv << 4) + (q << 2) + v;
      int col = (ni << 4) + rr;
      P[(size_t)ks2 * NROWS * N2DIM + (size_t)row * N2DIM + col] = accP[ni][v];
    }
  }
}

// ---------------- K3: sum partials, select leaf, add bias ------------------
__global__ __launch_bounds__(256) void k3_select(
    const float* __restrict__ P0, const float* __restrict__ P1,
    const float* __restrict__ bl2, const int* __restrict__ router,
    float* __restrict__ out) {
  int t = blockIdx.x * 256 + threadIdx.x;
  int b = t / 12, i4 = (t % 12) * 4;
  int sel = router[b];
  int cb = sel ? 48 : 0;
  int bb = sel ? 1488 : 0;
  float4 p0 = *(const float4*)(P0 + (size_t)b * N2DIM + cb + i4);
  float4 p1 = *(const float4*)(P1 + (size_t)b * N2DIM + cb + i4);
  float4 bz = *(const float4*)(bl2 + bb + i4);
  float4 r;
  r.x = p0.x + p1.x + bz.x;
  r.y = p0.y + p1.y + bz.y;
  r.z = p0.z + p1.z + bz.z;
  r.w = p0.w + p1.w + bz.w;
  *(float4*)(out + (size_t)b * 48 + i4) = r;
}

extern "C" void kernel_launch(void* const* d_in, const int* in_sizes, int n_in,
                              void* d_out, int out_size, void* d_ws, size_t ws_size,
                              hipStream_t stream) {
  const float* bd  = (const float*)d_in[0];
  const float* Wl1 = (const float*)d_in[1];
  const float* bl1 = (const float*)d_in[2];
  const float* Wl2 = (const float*)d_in[3];
  const float* bl2 = (const float*)d_in[4];
  const float* Wb1 = (const float*)d_in[5];
  const float* bb1 = (const float*)d_in[6];
  const float* Wb2 = (const float*)d_in[7];
  const float* bb2 = (const float*)d_in[8];

  char* ws = (char*)d_ws;
  ushort* x2bf  = (ushort*)(ws);                  // 16384*256*2  = 8,388,608
  ushort* wl1t  = (ushort*)(ws + 8388608);        // 2048*256*2   = 1,048,576
  ushort* w2t   = (ushort*)(ws + 9437184);        // 96*2048*2    =   393,216
  float*  P     = (float*)(ws + 76939264);        // 2*16384*96*4 = 12,582,912
  int*    router= (int*)(ws + 89522176);          // 16384*4      =    65,536
  ushort* wb1t  = (ushort*)(ws + 89587712);       // 512*128*2    =   131,072
  float*  part  = (float*)(ws + 89718784);        // 8*16384*4    =   524,288
  int*    list  = (int*)(ws + 90243072);          // 16384*4      =    65,536
  int*    counter=(int*)(ws + 90308608);          // 4
  float*  outp  = (float*)d_out;

  k0_convert<<<dim3(16384), dim3(256), 0, stream>>>(bd, Wl1, Wl2, Wb1,
                                                    x2bf, wl1t, w2t, wb1t);
  hipMemsetAsync(counter, 0, 4, stream);
  k1a_score<<<dim3(4, 128), dim3(256), 0, stream>>>(x2bf, wb1t, bb1, Wb2, part);
  k1b_classify<<<dim3(64), dim3(256), 0, stream>>>(part, bb2, router, list, counter);
  k1c_recheck<<<dim3(128), dim3(256), 0, stream>>>(bd, Wb1, Wb2, bb1, bb2,
                                                   list, counter, router);
  k2_fused<<<dim3(2, 256), dim3(256), 0, stream>>>(x2bf, wl1t, w2t, bl1, P);
  k3_select<<<dim3(768), dim3(256), 0, stream>>>(P, P + (size_t)NROWS * N2DIM, bl2,
                                                 router, outp);
}

// Round 4
// 173.672 us; speedup vs baseline: 1.0739x; 1.0739x over previous
//
#include <hip/hip_runtime.h>
#include <stdint.h>

typedef short bf16x8 __attribute__((ext_vector_type(8)));
typedef float f32x4 __attribute__((ext_vector_type(4)));

#define NROWS 16384
#define K1DIM 256
#define N1DIM 2048
#define N2DIM 96
#define MARGIN 0.03f

#define GLD16(g, l) __builtin_amdgcn_global_load_lds( \
    (const __attribute__((address_space(1))) uint32_t*)(g), \
    (__attribute__((address_space(3))) uint32_t*)(l), 16, 0, 0)

__device__ __forceinline__ ushort f2bf(float x) {
  union { float f; uint32_t u; } c; c.f = x;
  uint32_t u = c.u;
  return (ushort)((u + 0x7FFFu + ((u >> 16) & 1u)) >> 16);
}

// ---------------- K0: convert inputs to bf16 (x2, Wl1^T, W2sel^T, Wb1^T) ---
__global__ __launch_bounds__(256) void k0_convert(
    const float* __restrict__ bd, const float* __restrict__ Wl1,
    const float* __restrict__ Wl2, const float* __restrict__ Wb1,
    ushort* __restrict__ x2bf, ushort* __restrict__ wl1t,
    ushort* __restrict__ w2t, ushort* __restrict__ wb1t) {
  int i = blockIdx.x * 256 + threadIdx.x;
  if (i < NROWS * 256) x2bf[i] = f2bf(bd[i]);
  if (i < 2048 * 256) {  // wl1t[n][k] = Wl1[k][n]
    int n = i >> 8, k = i & 255;
    wl1t[i] = f2bf(Wl1[k * 2048 + n]);
  }
  if (i < 96 * 2048) {   // w2t[j][k] = Wl2[k][colmap(j)]
    int j = i >> 11, k = i & 2047;
    int col = (j < 48) ? j : (1440 + j);
    w2t[i] = f2bf(Wl2[k * 1536 + col]);
  }
  if (i < 512 * 128) {   // wb1t[j][m] = Wb1[m][j]
    int j = i >> 7, m = i & 127;
    wb1t[i] = f2bf(Wb1[m * 512 + j]);
  }
}

// ---------------- K1a: branch scores via bf16 MFMA -------------------------
__global__ __launch_bounds__(256) void k1a_score(
    const ushort* __restrict__ x2bf, const ushort* __restrict__ wb1t,
    const float* __restrict__ bb1, const float* __restrict__ Wb2,
    float* __restrict__ part) {
  __shared__ __align__(1024) ushort As[128 * 64];
  __shared__ __align__(1024) ushort Bs[128 * 64];
  const int t = threadIdx.x, ln = t & 63, wv = t >> 6;
  const int m0 = blockIdx.y << 7;
  const int n0 = blockIdx.x << 7;
  const int wm = (wv >> 1) << 6, wn = (wv & 1) << 6;
  const int rsub = ln >> 3, kc8 = ln & 7;
  const int q = ln >> 4, rr = ln & 15;

  f32x4 acc[4][4] = {};

  for (int k0 = 0; k0 < 128; k0 += 64) {
#pragma unroll
    for (int i = 0; i < 4; i++) {
      int inst = (wv << 2) + i;
      int row = (inst << 3) + rsub;
      GLD16(x2bf + (size_t)(m0 + row) * 256 + k0 + (kc8 << 3), As + (inst << 9));
      GLD16(wb1t + (size_t)(n0 + row) * 128 + k0 + (kc8 << 3), Bs + (inst << 9));
    }
    __syncthreads();
#pragma unroll
    for (int kk = 0; kk < 2; kk++) {
      int kb = ((kk << 2) + q) << 3;
      bf16x8 af[4], bfr[4];
#pragma unroll
      for (int mi = 0; mi < 4; mi++)
        af[mi] = *(const bf16x8*)(As + (((wm + (mi << 4) + rr)) << 6) + kb);
#pragma unroll
      for (int ni = 0; ni < 4; ni++)
        bfr[ni] = *(const bf16x8*)(Bs + (((wn + (ni << 4) + rr)) << 6) + kb);
#pragma unroll
      for (int mi = 0; mi < 4; mi++)
#pragma unroll
        for (int ni = 0; ni < 4; ni++)
          acc[mi][ni] = __builtin_amdgcn_mfma_f32_16x16x32_bf16(
              af[mi], bfr[ni], acc[mi][ni], 0, 0, 0);
    }
    __syncthreads();
  }

  float s4[4][4] = {};
#pragma unroll
  for (int ni = 0; ni < 4; ni++) {
    int col = n0 + wn + (ni << 4) + rr;
    float bias = bb1[col];
    float wdv = Wb2[col * 2 + 1] - Wb2[col * 2];
#pragma unroll
    for (int mi = 0; mi < 4; mi++) {
      f32x4 a = acc[mi][ni];
#pragma unroll
      for (int v = 0; v < 4; v++)
        s4[mi][v] += fmaxf(a[v] + bias, 0.f) * wdv;
    }
  }
#pragma unroll
  for (int off = 1; off <= 8; off <<= 1)
#pragma unroll
    for (int mi = 0; mi < 4; mi++)
#pragma unroll
      for (int v = 0; v < 4; v++)
        s4[mi][v] += __shfl_xor(s4[mi][v], off);

  if (rr == 0) {
    float* dst = part + (size_t)(blockIdx.x * 2 + (wv & 1)) * NROWS +
                 m0 + wm + (q << 2);
#pragma unroll
    for (int mi = 0; mi < 4; mi++) {
      float4 v4 = make_float4(s4[mi][0], s4[mi][1], s4[mi][2], s4[mi][3]);
      *(float4*)(dst + (mi << 4)) = v4;
    }
  }
}

// ---------------- K1b: sum partials, classify, compact marginal rows -------
__global__ __launch_bounds__(256) void k1b_classify(
    const float* __restrict__ part, const float* __restrict__ bb2,
    int* __restrict__ router, int* __restrict__ list, int* __restrict__ counter) {
  int t = blockIdx.x * 256 + threadIdx.x;
  float s = bb2[1] - bb2[0];
#pragma unroll
  for (int i = 0; i < 8; i++) s += part[i * NROWS + t];
  router[t] = (s >= 0.f) ? 1 : 0;
  if (fabsf(s) < MARGIN) {
    int idx = atomicAdd(counter, 1);
    list[idx] = t;
  }
}

// ---------------- K1c: exact fp32 recheck of marginal rows -----------------
__global__ __launch_bounds__(256) void k1c_recheck(
    const float* __restrict__ bd, const float* __restrict__ Wb1,
    const float* __restrict__ Wb2, const float* __restrict__ bb1,
    const float* __restrict__ bb2, const int* __restrict__ list,
    const int* __restrict__ counter, int* __restrict__ router) {
  const int ln = threadIdx.x & 63;
  const int wid = (blockIdx.x * 256 + threadIdx.x) >> 6;
  const int count = *counter;
  const float c = bb2[1] - bb2[0];

  for (int base = wid * 4; base < count; base += 512 * 4) {
    int rows[4];
#pragma unroll
    for (int r = 0; r < 4; r++) {
      int idx = base + r;
      rows[r] = list[(idx < count) ? idx : base];
    }
    float acc[4][8];
#pragma unroll
    for (int r = 0; r < 4; r++)
#pragma unroll
      for (int u = 0; u < 8; u++) acc[r][u] = 0.f;

    for (int m = 0; m < 128; m++) {
      float w[8];
#pragma unroll
      for (int u = 0; u < 8; u++) w[u] = Wb1[m * 512 + (u << 6) + ln];
#pragma unroll
      for (int r = 0; r < 4; r++) {
        float x = bd[(size_t)rows[r] * 256 + m];
#pragma unroll
        for (int u = 0; u < 8; u++) acc[r][u] = fmaf(x, w[u], acc[r][u]);
      }
    }
    float sc[4];
#pragma unroll
    for (int r = 0; r < 4; r++) {
      float s = 0.f;
#pragma unroll
      for (int u = 0; u < 8; u++) {
        int j = (u << 6) + ln;
        float wd = Wb2[j * 2 + 1] - Wb2[j * 2];
        s += fmaxf(acc[r][u] + bb1[j], 0.f) * wd;
      }
#pragma unroll
      for (int off = 1; off <= 32; off <<= 1) s += __shfl_xor(s, off);
      sc[r] = s + c;
    }
    if (ln == 0) {
#pragma unroll
      for (int r = 0; r < 4; r++)
        if (base + r < count) router[rows[r]] = (sc[r] >= 0.f) ? 1 : 0;
    }
  }
}

// ---------------- K2: FUSED GEMM1+GEMM2+select, XOR-swizzled LDS -----------
// LDS tiles store k-chunk (s ^ (row&7)) at slot s (via per-lane GLD16 source
// permute) -> b128 fragment reads hit all 32 banks (8-cyc floor).
// Epilogue: each wave owns 16 rows; atomicAdd partial (over this n-half's K)
// of the SELECTED leaf + bias (half 0 only) into zeroed d_out.
__global__ __launch_bounds__(256) void k2_fused(
    const ushort* __restrict__ x2bf, const ushort* __restrict__ wl1t,
    const ushort* __restrict__ w2t, const float* __restrict__ bl1,
    const float* __restrict__ bl2, const int* __restrict__ router,
    float* __restrict__ out) {
  __shared__ __align__(1024) ushort As[64 * 64];        // x2 tile [r][k-swz]
  __shared__ __align__(1024) ushort Bs[128 * 64];       // Wl1^T tile [n][k-swz]
  __shared__ __align__(1024) ushort Ws[2 * 96 * 64];    // w2 tile [half][n][k-swz]
  __shared__ __align__(1024) ushort Hs[64 * 128];       // hl tile [r][c-swz]
  const int t = threadIdx.x, ln = t & 63, wv = t >> 6;
  const int ks2 = blockIdx.x;       // n-half: 0,1
  const int m0 = blockIdx.y << 6;   // 64-row block
  const int q = ln >> 4, rr = ln & 15;
  const int rsub = ln >> 3;
  const int swz8 = ((ln & 7) ^ rsub) << 3;  // swizzled k-offset for GLD16 src

  f32x4 accP[6] = {};

  for (int nc = 0; nc < 8; nc++) {
    const int n0 = (ks2 << 10) + (nc << 7);

    // stage Ws (w2t[0..96][n0..n0+128]) as two [96][64] swizzled halves
#pragma unroll
    for (int j = 0; j < 6; j++) {
      int inst = wv * 6 + j;              // 0..23
      int h = inst / 12;
      int r12 = inst - h * 12;
      GLD16(w2t + (size_t)((r12 << 3) + rsub) * 2048 + n0 + (h << 6) + swz8,
            Ws + h * 6144 + (r12 << 9));
    }

    f32x4 acc1[4][2] = {};
    for (int k0 = 0; k0 < K1DIM; k0 += 64) {
#pragma unroll
      for (int i = 0; i < 2; i++) {
        int inst = (wv << 1) + i;
        GLD16(x2bf + (size_t)(m0 + (inst << 3) + rsub) * K1DIM + k0 + swz8,
              As + (inst << 9));
      }
#pragma unroll
      for (int i = 0; i < 4; i++) {
        int inst = (wv << 2) + i;
        GLD16(wl1t + (size_t)(n0 + (inst << 3) + rsub) * K1DIM + k0 + swz8,
              Bs + (inst << 9));
      }
      __syncthreads();
#pragma unroll
      for (int kk = 0; kk < 2; kk++) {
        int slot = ((kk << 2) + q);
        bf16x8 af[4], bfr[2];
#pragma unroll
        for (int mi = 0; mi < 4; mi++)
          af[mi] = *(const bf16x8*)(As + (((mi << 4) + rr) << 6) +
                                    ((slot ^ (rr & 7)) << 3));
#pragma unroll
        for (int ni = 0; ni < 2; ni++)
          bfr[ni] = *(const bf16x8*)(Bs + (((wv << 5) + (ni << 4) + rr) << 6) +
                                     ((slot ^ (rr & 7)) << 3));
#pragma unroll
        for (int mi = 0; mi < 4; mi++)
#pragma unroll
          for (int ni = 0; ni < 2; ni++)
            acc1[mi][ni] = __builtin_amdgcn_mfma_f32_16x16x32_bf16(
                af[mi], bfr[ni], acc1[mi][ni], 0, 0, 0);
      }
      __syncthreads();
    }

    // epilogue 1: bias + relu -> bf16 -> Hs (swizzled slot = (c>>3)^(row&15))
#pragma unroll
    for (int ni = 0; ni < 2; ni++) {
      int lcol = (wv << 5) + (ni << 4) + rr;
      int slotc = lcol >> 3;
      float bias = bl1[n0 + lcol];
#pragma unroll
      for (int mi = 0; mi < 4; mi++) {
        f32x4 a = acc1[mi][ni];
#pragma unroll
        for (int v = 0; v < 4; v++) {
          int lrow = (mi << 4) + (q << 2) + v;
          Hs[(lrow << 7) + ((slotc ^ (lrow & 15)) << 3) + (rr & 7)] =
              f2bf(fmaxf(a[v] + bias, 0.f));
        }
      }
    }
    __syncthreads();

    // G2: accP[wave's 16 rows][96] += Hs @ Ws   (K=128 chunk)
#pragma unroll
    for (int kk = 0; kk < 4; kk++) {
      int half = kk >> 1;
      int c2 = ((kk & 1) << 2) + q;        // within-half k-chunk 0..7
      int cH = (kk << 2) + q;              // Hs k-chunk 0..15
      bf16x8 ha = *(const bf16x8*)(Hs + (((wv << 4) + rr) << 7) +
                                   ((cH ^ rr) << 3));
#pragma unroll
      for (int ni = 0; ni < 6; ni++) {
        bf16x8 wb = *(const bf16x8*)(Ws + half * 6144 +
                                     (((ni << 4) + rr) << 6) +
                                     ((c2 ^ (rr & 7)) << 3));
        accP[ni] = __builtin_amdgcn_mfma_f32_16x16x32_bf16(ha, wb, accP[ni], 0, 0, 0);
      }
    }
    __syncthreads();
  }

  // fused select epilogue: wave owns rows m0+16*wv .. +15 (this n-half partial)
  {
    int rowb = m0 + (wv << 4) + (q << 2);
#pragma unroll
    for (int v = 0; v < 4; v++) {
      int row = rowb + v;
      int sel = router[row];
      float v0 = sel ? accP[3][v] : accP[0][v];
      float v1 = sel ? accP[4][v] : accP[1][v];
      float v2 = sel ? accP[5][v] : accP[2][v];
      if (ks2 == 0) {  // add bias exactly once
        int bb = sel ? 1488 : 0;
        v0 += bl2[bb + rr];
        v1 += bl2[bb + 16 + rr];
        v2 += bl2[bb + 32 + rr];
      }
      float* ob = out + (size_t)row * 48 + rr;
      atomicAdd(ob, v0);
      atomicAdd(ob + 16, v1);
      atomicAdd(ob + 32, v2);
    }
  }
}

extern "C" void kernel_launch(void* const* d_in, const int* in_sizes, int n_in,
                              void* d_out, int out_size, void* d_ws, size_t ws_size,
                              hipStream_t stream) {
  const float* bd  = (const float*)d_in[0];
  const float* Wl1 = (const float*)d_in[1];
  const float* bl1 = (const float*)d_in[2];
  const float* Wl2 = (const float*)d_in[3];
  const float* bl2 = (const float*)d_in[4];
  const float* Wb1 = (const float*)d_in[5];
  const float* bb1 = (const float*)d_in[6];
  const float* Wb2 = (const float*)d_in[7];
  const float* bb2 = (const float*)d_in[8];

  char* ws = (char*)d_ws;
  ushort* x2bf  = (ushort*)(ws);                  // 16384*256*2  = 8,388,608
  ushort* wl1t  = (ushort*)(ws + 8388608);        // 2048*256*2   = 1,048,576
  ushort* w2t   = (ushort*)(ws + 9437184);        // 96*2048*2    =   393,216
  int*    router= (int*)(ws + 89522176);          // 16384*4
  ushort* wb1t  = (ushort*)(ws + 89587712);       // 512*128*2
  float*  part  = (float*)(ws + 89718784);        // 8*16384*4
  int*    list  = (int*)(ws + 90243072);          // 16384*4
  int*    counter=(int*)(ws + 90308608);          // 4
  float*  outp  = (float*)d_out;

  k0_convert<<<dim3(16384), dim3(256), 0, stream>>>(bd, Wl1, Wl2, Wb1,
                                                    x2bf, wl1t, w2t, wb1t);
  hipMemsetAsync(counter, 0, 4, stream);
  hipMemsetAsync(outp, 0, (size_t)out_size * 4, stream);
  k1a_score<<<dim3(4, 128), dim3(256), 0, stream>>>(x2bf, wb1t, bb1, Wb2, part);
  k1b_classify<<<dim3(64), dim3(256), 0, stream>>>(part, bb2, router, list, counter);
  k1c_recheck<<<dim3(128), dim3(256), 0, stream>>>(bd, Wb1, Wb2, bb1, bb2,
                                                   list, counter, router);
  k2_fused<<<dim3(2, 256), dim3(256), 0, stream>>>(x2bf, wl1t, w2t, bl1, bl2,
                                                   router, outp);
}